// Round 6
// baseline (68.533 us; speedup 1.0000x reference)
//
#include <hip/hip_runtime.h>
#include <math.h>

// Problem constants (from reference)
#define B_    64
#define C_    8
#define T_    2048
#define K_    16
#define NF_   9
#define FEAT_ 144   // C_*NF_*2
#define MLP_  16
#define H1_   64
#define H2_   32
#define EFF_  60
#define W_    1988  // T_-EFF_
#define NWCH_ 8     // ceil(W_/256) for mono path
#define NCHK2 32    // stage2 w-chunks of 64
#define NG_   4     // channel groups (2 channels each)
#define PI_F  3.14159265358979323846f
#define STR1  20    // LDS row stride (floats) for w1 rows: sub-groups hit disjoint banks
#define STR2  36    // LDS row stride (floats) for w2t rows

// Twiddles: angle(t) = 2*pi*t/16; f[n] = sum win[k]*exp(-i*2*pi*n*k/16)
constexpr float COS16[16] = {
   1.0f,  0.92387953251128674f,  0.70710678118654752f,  0.38268343236508977f,
   0.0f, -0.38268343236508977f, -0.70710678118654752f, -0.92387953251128674f,
  -1.0f, -0.92387953251128674f, -0.70710678118654752f, -0.38268343236508977f,
   0.0f,  0.38268343236508977f,  0.70710678118654752f,  0.92387953251128674f };
constexpr float SIN16F[16] = {
   0.0f,  0.38268343236508977f,  0.70710678118654752f,  0.92387953251128674f,
   1.0f,  0.92387953251128674f,  0.70710678118654752f,  0.38268343236508977f,
   0.0f, -0.38268343236508977f, -0.70710678118654752f, -0.92387953251128674f,
  -1.0f, -0.92387953251128674f, -0.70710678118654752f, -0.38268343236508977f };

// ---- fast device math (hw transcendentals) ----
__device__ __forceinline__ float fast_log1p(float s) {
  return __builtin_amdgcn_logf(1.0f + s) * 0.69314718055994531f;
}

__device__ __forceinline__ float atanpi_poly(float r) {
  const float s2 = r * r;
  float p = -0.0037310f;
  p = fmaf(p, s2,  0.0167600f);
  p = fmaf(p, s2, -0.0370617f);
  p = fmaf(p, s2,  0.0616068f);
  p = fmaf(p, s2, -0.10587734f);
  p = fmaf(p, s2,  0.31830265f);
  return r * p;
}

__device__ __forceinline__ float atan2pi_fast(float im, float re) {
  const float ax = fabsf(re), ay = fabsf(im);
  const float mx = fmaxf(ax, ay), mn = fminf(ax, ay);
  const float r = mn * __builtin_amdgcn_rcpf(fmaxf(mx, 1e-37f));
  float t = atanpi_poly(r);
  t = (ay > ax) ? 0.5f - t : t;
  t = (__float_as_uint(re) & 0x80000000u) ? 1.0f - t : t;  // signbit(re), handles -0
  return copysignf(t, im);                                  // im=+0 keeps +pi convention
}

__device__ __forceinline__ float fast_tanh(float z) {
  const float az = fabsf(z);
  const float e = __builtin_amdgcn_exp2f(-2.8853900817779268f * az);  // exp(-2|z|)
  const float th = fmaf(-2.0f, e * __builtin_amdgcn_rcpf(1.0f + e), 1.0f);
  return copysignf(th, z);
}

// DFT + feature + projection partial for ONE channel, accumulated into pacc.
__device__ __forceinline__ void dft_proj_channel(const float* __restrict__ xc,
                                                 const float* __restrict__ PWt,
                                                 int c, float* pacc) {
  float win[K_];
  #pragma unroll
  for (int k = 0; k < K_; k++) win[k] = xc[k * 4];
  float ae[8], bo[8];
  #pragma unroll
  for (int k = 0; k < 8; k++) { ae[k] = win[k] + win[k+8]; bo[k] = win[k] - win[k+8]; }
  #pragma unroll
  for (int n = 0; n < NF_; n++) {
    float re = 0.f, im = 0.f;
    #pragma unroll
    for (int k = 0; k < 8; k++) {
      const float v = (n & 1) ? bo[k] : ae[k];
      const int t = (n * k) & 15;
      re = fmaf(v,  COS16[t],  re);
      im = fmaf(v, -SIN16F[t], im);   // im stays +0.0 exactly for n=0,8
    }
    const float s   = __builtin_amdgcn_sqrtf(fmaf(re, re, im * im));
    const float mag = fast_log1p(s);
    const float ph  = atan2pi_fast(im, re);
    const float* rm = PWt + (size_t)((c * NF_ + n) * 2) * MLP_;  // wave-uniform -> s_load
    #pragma unroll
    for (int j = 0; j < MLP_; j++)
      pacc[j] = fmaf(mag, rm[j], fmaf(ph, rm[MLP_ + j], pacc[j]));
  }
}

// MLP tail for mono fallback (scalar-load weights).
__device__ __forceinline__ float mlp_tail(const float* p,
                                          const float* __restrict__ w1, const float* __restrict__ b1,
                                          const float* __restrict__ W2t, const float* __restrict__ b2,
                                          const float* __restrict__ out_w, const float* __restrict__ out_b) {
  float h2a[H2_];
  #pragma unroll
  for (int m = 0; m < H2_; m++) h2a[m] = b2[m];
  #pragma unroll 8
  for (int i = 0; i < H1_; i++) {
    const float* r1 = w1 + i * MLP_;
    float acc = b1[i];
    #pragma unroll
    for (int j = 0; j < MLP_; j++) acc = fmaf(p[j], r1[j], acc);
    const float h1v = fmaxf(acc, 0.f);
    const float* r2 = W2t + i * H2_;
    #pragma unroll
    for (int m = 0; m < H2_; m++) h2a[m] = fmaf(h1v, r2[m], h2a[m]);
  }
  float o = out_b[0];
  #pragma unroll
  for (int m = 0; m < H2_; m++) o = fmaf(fmaxf(h2a[m], 0.f), out_w[m], o);
  return o;
}

// ---------------- Kernel 0: fused setup (softmax + weight transposes) ----------------
__global__ __launch_bounds__(256) void setup_kernel(const float* __restrict__ agg,
                                                    float* __restrict__ wts,
                                                    const float* __restrict__ pw,
                                                    const float* __restrict__ w2,
                                                    float* __restrict__ PWt,
                                                    float* __restrict__ W2t) {
  if (blockIdx.x == 0) {
    __shared__ float red[256];
    const int tid = threadIdx.x;
    float m = -INFINITY;
    for (int i = tid; i < W_; i += 256) m = fmaxf(m, agg[i]);
    red[tid] = m; __syncthreads();
    for (int s = 128; s > 0; s >>= 1) { if (tid < s) red[tid] = fmaxf(red[tid], red[tid+s]); __syncthreads(); }
    const float mx = red[0];
    __syncthreads();
    float sum = 0.f;
    for (int i = tid; i < W_; i += 256) sum += expf(agg[i] - mx);
    red[tid] = sum; __syncthreads();
    for (int s = 128; s > 0; s >>= 1) { if (tid < s) red[tid] += red[tid+s]; __syncthreads(); }
    const float inv = 1.f / red[0];
    for (int i = tid; i < W_; i += 256) wts[i] = expf(agg[i] - mx) * inv;
  } else {
    const int tid = (blockIdx.x - 1) * 256 + threadIdx.x;
    if (tid < MLP_ * FEAT_) {
      const int j = tid / FEAT_, f = tid - j * FEAT_;  // pw[j][f]
      PWt[f * MLP_ + j] = pw[tid];
    }
    if (tid < H2_ * H1_) {
      const int m = tid >> 6, i = tid & 63;            // w2[m][i]
      W2t[i * H2_ + m] = w2[tid];
    }
  }
}

// ---------------- Stage 1: DFT+proj partials, 4x parallelism ----------------
// grid (NWCH_, B_, NG_); pf layout [b][g][q][W_][4] -> 16B-consecutive lanes.
__global__ __launch_bounds__(256) void tcn_stage1(const float* __restrict__ x,
                                                  const float* __restrict__ PWt,
                                                  float* __restrict__ pf) {
  const int tid = threadIdx.x;
  const int b = blockIdx.y, g = blockIdx.z;
  const int w = blockIdx.x * 256 + tid;
  if (w >= W_) return;
  float pacc[MLP_];
  #pragma unroll
  for (int j = 0; j < MLP_; j++) pacc[j] = 0.f;
  #pragma unroll 1
  for (int cc = 0; cc < 2; cc++) {
    const int c = g * 2 + cc;
    dft_proj_channel(x + ((size_t)b * C_ + c) * T_ + w, PWt, c, pacc);
  }
  #pragma unroll
  for (int q = 0; q < 4; q++)
    *reinterpret_cast<float4*>(pf + ((size_t)((b * NG_ + g) * 4 + q) * W_ + w) * 4) =
        make_float4(pacc[4*q+0], pacc[4*q+1], pacc[4*q+2], pacc[4*q+3]);
}

// ---------------- Stage 2: tail with 4 sub-lanes per w, shuffle reduction ----------------
// grid (NCHK2, B_): 64 w per block; lane = (sub<<4)|wloc within each wave.
__global__ __launch_bounds__(256) void tcn_stage2(
    const float* __restrict__ pf, const float* __restrict__ proj_b,
    const float* __restrict__ w1, const float* __restrict__ b1,
    const float* __restrict__ W2t, const float* __restrict__ b2,
    const float* __restrict__ out_w, const float* __restrict__ out_b,
    const float* __restrict__ wts, float* __restrict__ partials) {
  __shared__ __align__(16) float W1p[H1_ * STR1];
  __shared__ __align__(16) float W2p[H1_ * STR2];
  __shared__ float B1s[H1_];
  __shared__ float red[256];
  const int tid = threadIdx.x;
  for (int idx = tid; idx < H1_ * MLP_; idx += 256) {
    const int i = idx >> 4, j = idx & 15;
    W1p[i * STR1 + j] = w1[idx];
  }
  for (int idx = tid; idx < H1_ * H2_; idx += 256) {
    const int i = idx >> 5, m = idx & 31;
    W2p[i * STR2 + m] = W2t[idx];
  }
  if (tid < H1_) B1s[tid] = b1[tid];
  __syncthreads();

  const int lane = tid & 63;
  const int wave = tid >> 6;
  const int wloc = lane & 15;
  const int sub  = lane >> 4;
  const int b = blockIdx.y;
  const int w = blockIdx.x * 64 + wave * 16 + wloc;
  const int wl = (w < W_) ? w : 0;   // clamp loads; masked at the end

  // gather pacc (fixed g order -> deterministic)
  float pacc[MLP_];
  #pragma unroll
  for (int j = 0; j < MLP_; j++) pacc[j] = proj_b[j];
  #pragma unroll
  for (int g = 0; g < NG_; g++) {
    #pragma unroll
    for (int q = 0; q < 4; q++) {
      const float4 a = *reinterpret_cast<const float4*>(
          pf + ((size_t)((b * NG_ + g) * 4 + q) * W_ + wl) * 4);
      pacc[4*q+0] += a.x; pacc[4*q+1] += a.y; pacc[4*q+2] += a.z; pacc[4*q+3] += a.w;
    }
  }
  float p[MLP_];
  #pragma unroll
  for (int j = 0; j < MLP_; j++) p[j] = fast_tanh(pacc[j]) * PI_F;

  // 16 H1 rows per sub-lane: i = sub + 4*ii (disjoint bank quads per sub)
  float h2a[H2_];
  #pragma unroll
  for (int m = 0; m < H2_; m++) h2a[m] = 0.f;
  #pragma unroll 4
  for (int ii = 0; ii < 16; ii++) {
    const int i = sub + ii * 4;
    const float4* r1 = reinterpret_cast<const float4*>(&W1p[i * STR1]);
    float acc = B1s[i];
    #pragma unroll
    for (int q = 0; q < 4; q++) {
      const float4 a = r1[q];
      acc = fmaf(p[4*q+0], a.x, acc);
      acc = fmaf(p[4*q+1], a.y, acc);
      acc = fmaf(p[4*q+2], a.z, acc);
      acc = fmaf(p[4*q+3], a.w, acc);
    }
    const float h1v = fmaxf(acc, 0.f);
    const float4* r2 = reinterpret_cast<const float4*>(&W2p[i * STR2]);
    #pragma unroll
    for (int q = 0; q < 8; q++) {
      const float4 a = r2[q];
      h2a[4*q+0] = fmaf(h1v, a.x, h2a[4*q+0]);
      h2a[4*q+1] = fmaf(h1v, a.y, h2a[4*q+1]);
      h2a[4*q+2] = fmaf(h1v, a.z, h2a[4*q+2]);
      h2a[4*q+3] = fmaf(h1v, a.w, h2a[4*q+3]);
    }
  }
  // butterfly across sub bits (lane bits 4,5) -- wave-internal, no barrier
  #pragma unroll
  for (int m = 0; m < H2_; m++) h2a[m] += __shfl_xor(h2a[m], 16, 64);
  #pragma unroll
  for (int m = 0; m < H2_; m++) h2a[m] += __shfl_xor(h2a[m], 32, 64);

  float val = 0.f;
  if (sub == 0 && w < W_) {
    float o = out_b[0];
    #pragma unroll
    for (int m = 0; m < H2_; m++) o = fmaf(fmaxf(h2a[m] + b2[m], 0.f), out_w[m], o);
    val = o * wts[w];
  }
  red[tid] = val; __syncthreads();
  for (int s = 128; s > 0; s >>= 1) { if (tid < s) red[tid] += red[tid+s]; __syncthreads(); }
  if (tid == 0) partials[b * NCHK2 + blockIdx.x] = red[0];
}

// ---------------- Fallback: proven monolithic kernel (R2 structure) ----------------
__global__ __launch_bounds__(256) void tcn_mono(const float* __restrict__ x,
                                                const float* __restrict__ PWt, const float* __restrict__ proj_b,
                                                const float* __restrict__ w1, const float* __restrict__ b1,
                                                const float* __restrict__ W2t, const float* __restrict__ b2,
                                                const float* __restrict__ out_w, const float* __restrict__ out_b,
                                                const float* __restrict__ wts, float* __restrict__ partials) {
  __shared__ float red[256];
  const int tid = threadIdx.x;
  const int b = blockIdx.y;
  const int w = blockIdx.x * 256 + tid;
  float val = 0.f;
  if (w < W_) {
    float pacc[MLP_];
    #pragma unroll
    for (int j = 0; j < MLP_; j++) pacc[j] = proj_b[j];
    #pragma unroll 1
    for (int c = 0; c < C_; c++)
      dft_proj_channel(x + ((size_t)b * C_ + c) * T_ + w, PWt, c, pacc);
    float p[MLP_];
    #pragma unroll
    for (int j = 0; j < MLP_; j++) p[j] = fast_tanh(pacc[j]) * PI_F;
    val = mlp_tail(p, w1, b1, W2t, b2, out_w, out_b) * wts[w];
  }
  red[tid] = val; __syncthreads();
  for (int s = 128; s > 0; s >>= 1) { if (tid < s) red[tid] += red[tid+s]; __syncthreads(); }
  if (tid == 0) partials[b * NWCH_ + blockIdx.x] = red[0];
}

// ---------------- finalize ----------------
__global__ void finalize_kernel(const float* __restrict__ partials, float* __restrict__ out, int nchk) {
  const int b = threadIdx.x;
  if (b < B_) {
    float s = 0.f;
    for (int c = 0; c < nchk; c++) s += partials[b * nchk + c];
    out[b] = s;
  }
}

extern "C" void kernel_launch(void* const* d_in, const int* in_sizes, int n_in,
                              void* d_out, int out_size, void* d_ws, size_t ws_size,
                              hipStream_t stream) {
  const float* x      = (const float*)d_in[0];
  const float* proj_w = (const float*)d_in[1];
  const float* proj_b = (const float*)d_in[2];
  const float* w1     = (const float*)d_in[3];
  const float* b1     = (const float*)d_in[4];
  const float* w2     = (const float*)d_in[5];
  const float* b2     = (const float*)d_in[6];
  const float* out_w  = (const float*)d_in[7];
  const float* out_b  = (const float*)d_in[8];
  const float* agg_w  = (const float*)d_in[9];

  float* wts      = (float*)d_ws;                    // W_ floats (2048 slot)
  float* partials = (float*)d_ws + 2048;             // up to B_*NCHK2 = 2048 floats
  float* PWt      = (float*)d_ws + 4096;             // FEAT_*MLP_ = 2304 floats
  float* W2t      = (float*)d_ws + 4096 + 2304;      // H1_*H2_ = 2048 floats
  float* pf       = (float*)d_ws + 16384;            // B_*NG_*4*W_*4 floats

  const size_t need = ((size_t)16384 + (size_t)B_ * NG_ * W_ * MLP_) * sizeof(float);

  setup_kernel<<<10, 256, 0, stream>>>(agg_w, wts, proj_w, w2, PWt, W2t);
  if (ws_size >= need) {
    tcn_stage1<<<dim3(NWCH_, B_, NG_), 256, 0, stream>>>(x, PWt, pf);
    tcn_stage2<<<dim3(NCHK2, B_), 256, 0, stream>>>(pf, proj_b, w1, b1, W2t, b2,
                                                    out_w, out_b, wts, partials);
    finalize_kernel<<<1, 64, 0, stream>>>(partials, (float*)d_out, NCHK2);
  } else {
    tcn_mono<<<dim3(NWCH_, B_), 256, 0, stream>>>(x, PWt, proj_b, w1, b1, W2t, b2,
                                                  out_w, out_b, wts, partials);
    finalize_kernel<<<1, 64, 0, stream>>>(partials, (float*)d_out, NWCH_);
  }
}